// Round 2
// baseline (16302.357 us; speedup 1.0000x reference)
//
#include <hip/hip_runtime.h>
#include <math.h>

#define NSTATES 1024
#define TT      4096
#define DD      20

#define FW_BLOCKS  256     // one wave per block; 4 j's per wave
#define FW_THREADS 64

#define SENT 0x7FC00000u   // canonical NaN: computed column values are never NaN

// workspace layout (bytes)
#define OFF_LAT   ((size_t)0)               // 4 MB  logA transposed: lat[j*N+k] = log(trans[k][j])
#define OFF_E     ((size_t)4 << 20)         // 16 MB emissions E[t*N+n]
#define OFF_COLS  ((size_t)20 << 20)        // 16 MB per-step columns cols[t*N+j]
#define OFF_PTR   ((size_t)36 << 20)        // 8 MB  u16 backpointers, rows 1..T-1

typedef unsigned int u32;

__global__ void k_init(uint4* __restrict__ cols4) {
    // fill 16 MB of cols with the sentinel (4M words = 1M uint4)
    int id = blockIdx.x * 256 + threadIdx.x;
    cols4[id] = make_uint4(SENT, SENT, SENT, SENT);
}

__global__ void k_logtrans(const float* __restrict__ tr, float* __restrict__ lat) {
    int id = blockIdx.x * 256 + threadIdx.x;        // 1M threads
    int k = id >> 10, j = id & 1023;
    lat[(size_t)j * NSTATES + k] = logf(tr[id]);    // coalesced read, strided write (one-time)
}

__global__ void k_emis(const float* __restrict__ ev, const float* __restrict__ epar,
                       const float* __restrict__ prior, float* __restrict__ E,
                       float* __restrict__ cols) {
    int n = blockIdx.x * 256 + threadIdx.x;         // 4 x 256 = 1024
    int t = blockIdx.y;                             // 0..4095
    const float* ep = epar + (size_t)n * (2 * DD);
    const float* x  = ev + (size_t)t * DD;
    float acc = 0.0f;
    #pragma unroll
    for (int d = 0; d < DD; ++d) {
        float m = ep[2 * d];
        float s = ep[2 * d + 1];
        // faithful to reference: p = (2*pi*s)^(-0.5) * exp(-(x-m)^2/(2*s^2)); logp = log(p)
        float tp   = 6.2831853071795864769f * s;
        float coef = 1.0f / sqrtf(tp);
        float df   = x[d] - m;
        float num  = df * df;
        float den  = 2.0f * (s * s);
        float p    = coef * expf(-num / den);
        acc += logf(p);                             // -inf propagates; values are never NaN
    }
    E[(size_t)t * NSTATES + n] = acc;
    if (t == 0) cols[n] = logf(prior[n]) + acc;     // col0 = log(prior) + logp0 (overwrites sentinel)
}

// Self-timed wavefront forward pass: one wave per block, 4 j's per wave,
// zero barriers in the main loop. Each wave: poll the full prev column
// itself (16 agent-scope relaxed loads/lane -- the coherence primitive
// proven in the previous version) -> stage to wave-private padded LDS ->
// scan 64 k's/lane against a VGPR-resident lat slice -> shfl butterfly
// combine -> publish. lat never touches memory after the prologue.
__global__ __launch_bounds__(FW_THREADS, 1) void k_forward(
    const float* __restrict__ lat, const float* __restrict__ E,
    float* __restrict__ cols, unsigned short* __restrict__ bptr)
{
    // padded [16][68] floats: seg row stride 68 (=4 mod 32 words) spreads the
    // 16 distinct b128 read addresses across 8 start-bank-groups x2 broadcast
    // (optimal); the 64 distinct b128 writes land 8 per start-bank-group
    // (the 1KB/wave minimum -- no excess conflict).
    __shared__ __align__(16) float prevs[16 * 68];
    const int lane = threadIdx.x;             // 0..63
    const int seg  = lane & 15;               // k-segment: [seg*64, seg*64+64)
    const int j    = blockIdx.x * 4 + (lane >> 4);
    const float lat00 = lat[0];               // log trans[0][0], for the j==0 quirk

    // preload this lane's lat slice into registers (loop-invariant, 64 VGPRs)
    float4 latr[16];
    {
        const float* lrow = lat + (size_t)j * NSTATES + seg * 64;
        #pragma unroll
        for (int u = 0; u < 16; ++u) latr[u] = *(const float4*)(lrow + u * 4);
    }

    // lane l polls words k=[l*16, l*16+16) -> padded row l>>2, col (l&3)*16
    float* dstp = &prevs[(lane >> 2) * 68 + (lane & 3) * 16];
    const float* rowp = &prevs[seg * 68];

    for (int t = 1; t < TT; ++t) {
        // E load issued before the poll: its latency drains under the poll's
        // first vmcnt wait instead of sitting after the combine.
        float e = E[(size_t)t * NSTATES + j];

        // ---- poll previous column: 16 agent-scope relaxed word loads/lane,
        // per-lane exit so ready lanes stop generating traffic.
        const u32* p = (const u32*)(cols + (size_t)(t - 1) * NSTATES) + lane * 16;
        u32 w[16];
        for (;;) {
            #pragma unroll
            for (int u = 0; u < 16; ++u)
                w[u] = __hip_atomic_load(p + u, __ATOMIC_RELAXED, __HIP_MEMORY_SCOPE_AGENT);
            bool ok = true;
            #pragma unroll
            for (int u = 0; u < 16; ++u) ok &= (w[u] != SENT);
            if (ok) break;
            __builtin_amdgcn_s_sleep(1);
        }

        // ---- stage to wave-private LDS (4 x b128 per lane).
        // Same-wave ds ordering + explicit lgkmcnt drain; sched_barrier stops
        // the compiler hoisting the dependent ds_reads above the wait (rule #18).
        #pragma unroll
        for (int c = 0; c < 4; ++c) {
            float4 v;
            v.x = __uint_as_float(w[4 * c + 0]);
            v.y = __uint_as_float(w[4 * c + 1]);
            v.z = __uint_as_float(w[4 * c + 2]);
            v.w = __uint_as_float(w[4 * c + 3]);
            *(float4*)(dstp + 4 * c) = v;
        }
        asm volatile("s_waitcnt lgkmcnt(0)" ::: "memory");
        __builtin_amdgcn_sched_barrier(0);

        // ---- scan this lane's 64 k's: first-max (strict >, ascending k)
        float best = -__builtin_inff();
        int bidx = seg * 64;
        #pragma unroll
        for (int u = 0; u < 16; ++u) {
            float4 q = *(const float4*)(rowp + u * 4);
            float4 wv = latr[u];
            int k0 = seg * 64 + u * 4;
            float v0 = q.x + wv.x;
            float v1 = q.y + wv.y;
            float v2 = q.z + wv.z;
            float v3 = q.w + wv.w;
            if (v0 > best) { best = v0; bidx = k0;     }
            if (v1 > best) { best = v1; bidx = k0 + 1; }
            if (v2 > best) { best = v2; bidx = k0 + 2; }
            if (v3 > best) { best = v3; bidx = k0 + 3; }
        }

        // ---- combine 16 segment partials within the 16-lane group:
        // butterfly with tie -> smaller k == sequential first-max. No LDS, no sync.
        #pragma unroll
        for (int m = 8; m; m >>= 1) {
            float ov = __shfl_xor(best, m);
            int   oi = __shfl_xor(bidx, m);
            if (ov > best || (ov == best && oi < bidx)) { best = ov; bidx = oi; }
        }

        // ---- publish (one lane per j)
        if ((lane & 15) == 0) {
            float val = best;
            // reference quirk: j==0 value forced from state 0. Only block 0
            // lane 0 hits this; its first polled word w[0] IS cols[t-1][0].
            if (j == 0) val = __uint_as_float(w[0]) + lat00;
            float out = val + e;
            __hip_atomic_store((u32*)(cols + (size_t)t * NSTATES) + j,
                               __float_as_uint(out), __ATOMIC_RELAXED,
                               __HIP_MEMORY_SCOPE_AGENT);
            bptr[(size_t)t * NSTATES + j] = (unsigned short)bidx;  // true argmax
        }
    }
}

#define BTC 24  // ptr rows per LDS chunk (48 KB)
__global__ void k_backtrace(const float* __restrict__ lastcol,
                            const unsigned short* __restrict__ bptr,
                            int* __restrict__ seq)
{
    __shared__ unsigned short ring[BTC][NSTATES];
    __shared__ int s_front;
    const int lane = threadIdx.x;   // 64 threads = 1 wave

    // last = first-max argmax over final column
    float best = -__builtin_inff();
    int bi = 0;
    for (int n2 = lane; n2 < NSTATES; n2 += 64) {
        float v = lastcol[n2];
        if (v > best) { best = v; bi = n2; }
    }
    #pragma unroll
    for (int off = 32; off > 0; off >>= 1) {
        float ov = __shfl_xor(best, off);
        int   oi = __shfl_xor(bi, off);
        if (ov > best || (ov == best && oi < bi)) { best = ov; bi = oi; }
    }
    if (lane == 0) { seq[TT] = bi; seq[TT - 1] = bi; s_front = bi; }
    __syncthreads();

    // chase rows r = T-1 .. 1 (seq[r-1] = ptr[r][front]) in descending LDS chunks
    for (int rhi = TT - 1; rhi >= 1; rhi -= BTC) {
        int rlo = rhi - (BTC - 1);
        if (rlo < 1) rlo = 1;
        for (int rr = rlo; rr <= rhi; ++rr) {
            const uint4* src = (const uint4*)(bptr + (size_t)rr * NSTATES);
            uint4* dst = (uint4*)(&ring[rr - rlo][0]);
            dst[lane]      = src[lane];
            dst[lane + 64] = src[lane + 64];
        }
        __syncthreads();
        if (lane == 0) {
            int front = s_front;
            for (int r = rhi; r >= rlo; --r) {
                front = (int)ring[r - rlo][front];
                seq[r - 1] = front;
            }
            s_front = front;
        }
        __syncthreads();
    }
}

extern "C" void kernel_launch(void* const* d_in, const int* in_sizes, int n_in,
                              void* d_out, int out_size, void* d_ws, size_t ws_size,
                              hipStream_t stream) {
    const float* ev    = (const float*)d_in[0];   // [T, D]
    const float* prior = (const float*)d_in[1];   // [N]
    const float* tr    = (const float*)d_in[2];   // [N, N]
    const float* epar  = (const float*)d_in[3];   // [N, D, 2]
    int* seq = (int*)d_out;                       // [T+1]
    char* ws = (char*)d_ws;
    float* lat  = (float*)(ws + OFF_LAT);
    float* E    = (float*)(ws + OFF_E);
    float* cols = (float*)(ws + OFF_COLS);
    unsigned short* bptr = (unsigned short*)(ws + OFF_PTR);

    k_init<<<4096, 256, 0, stream>>>((uint4*)cols);              // sentinel-fill 16 MB
    k_logtrans<<<4096, 256, 0, stream>>>(tr, lat);
    k_emis<<<dim3(4, TT), 256, 0, stream>>>(ev, epar, prior, E, cols);
    k_forward<<<FW_BLOCKS, FW_THREADS, 0, stream>>>(lat, E, cols, bptr);
    k_backtrace<<<1, 64, 0, stream>>>(cols + (size_t)(TT - 1) * NSTATES, bptr, seq);
}

// Round 3
// 10781.041 us; speedup vs baseline: 1.5121x; 1.5121x over previous
//
#include <hip/hip_runtime.h>
#include <math.h>

#define NSTATES 1024
#define TT      4096
#define DD      20

#define FW_BLOCKS  64
#define FW_THREADS 256
#define JPB  16      // j per block   (FW_BLOCKS * JPB = NSTATES)
#define NSEG 16      // k segments    (JPB * NSEG = FW_THREADS)
#define KSEG 64      // k per segment (NSEG * KSEG = NSTATES)

#define SENT 0x7FC00000u   // canonical NaN: computed column values are never NaN

// workspace layout (bytes)
#define OFF_LAT   ((size_t)0)               // 4 MB  logA transposed: lat[j*N+k] = log(trans[k][j])
#define OFF_E     ((size_t)4 << 20)         // 16 MB emissions E[t*N+n]
#define OFF_COLS  ((size_t)20 << 20)        // 16 MB per-step columns cols[t*N+j]
#define OFF_PTR   ((size_t)36 << 20)        // 8 MB  u16 backpointers, rows 1..T-1

typedef unsigned int u32;

__global__ void k_init(uint4* __restrict__ cols4) {
    // fill 16 MB of cols with the sentinel (4M words = 1M uint4)
    int id = blockIdx.x * 256 + threadIdx.x;
    cols4[id] = make_uint4(SENT, SENT, SENT, SENT);
}

__global__ void k_logtrans(const float* __restrict__ tr, float* __restrict__ lat) {
    int id = blockIdx.x * 256 + threadIdx.x;        // 1M threads
    int k = id >> 10, j = id & 1023;
    lat[(size_t)j * NSTATES + k] = logf(tr[id]);    // coalesced read, strided write (one-time)
}

__global__ void k_emis(const float* __restrict__ ev, const float* __restrict__ epar,
                       const float* __restrict__ prior, float* __restrict__ E,
                       float* __restrict__ cols) {
    int n = blockIdx.x * 256 + threadIdx.x;         // 4 x 256 = 1024
    int t = blockIdx.y;                             // 0..4095
    const float* ep = epar + (size_t)n * (2 * DD);
    const float* x  = ev + (size_t)t * DD;
    float acc = 0.0f;
    #pragma unroll
    for (int d = 0; d < DD; ++d) {
        float m = ep[2 * d];
        float s = ep[2 * d + 1];
        // faithful to reference: p = (2*pi*s)^(-0.5) * exp(-(x-m)^2/(2*s^2)); logp = log(p)
        float tp   = 6.2831853071795864769f * s;
        float coef = 1.0f / sqrtf(tp);
        float df   = x[d] - m;
        float num  = df * df;
        float den  = 2.0f * (s * s);
        float p    = coef * expf(-num / den);
        acc += logf(p);                             // -inf propagates; values are never NaN
    }
    E[(size_t)t * NSTATES + n] = acc;
    if (t == 0) cols[n] = logf(prior[n]) + acc;     // col0 = log(prior) + logp0 (overwrites sentinel)
}

// Forward pass, round-0 comms (proven fastest) + intra-block overhead removal:
//   - per-thread 4-word poll of the previous column (identical protocol)
//   - single 64B coalesced publish by wave-0 lanes 0..15 (identical protocol)
//   - NEW: lat slice VGPR-resident (no per-step L2 reads on the chain)
//   - NEW: tid remap (seg=tid>>4) -> shfl_xor seg-combine in-wave, 4-deep
//          serial wave-combine; 2 barriers/step instead of 3
//   - NEW: padded float4 LDS staging (bank-conflict-free)
//   - NEW: E prefetch issued before the poll (latency hidden under poll RTT)
__global__ __launch_bounds__(FW_THREADS, 1) void k_forward(
    const float* __restrict__ lat, const float* __restrict__ E,
    float* __restrict__ cols, unsigned short* __restrict__ bptr)
{
    // padded [16][68]: row r holds words [r*64, r*64+64) of the prev column.
    __shared__ __align__(16) float prevs[NSEG * 68];
    __shared__ float          smaxw[4][JPB];   // per-wave partials (segs 4w..4w+3)
    __shared__ unsigned short sidxw[4][JPB];
    const int tid  = threadIdx.x;
    const int seg  = tid >> 4;                  // 0..15: k in [seg*64, seg*64+64)
    const int jj   = tid & (JPB - 1);
    const int wav  = tid >> 6;                  // wave id 0..3 (holds segs 4w..4w+3)
    const int j0   = blockIdx.x * JPB;
    const int j    = j0 + jj;
    const float lat00 = lat[0];                 // log trans[0][0], for the j==0 quirk

    // preload this thread's lat slice into registers (loop-invariant, 64 VGPRs)
    float4 latr[16];
    {
        const float* lrow = lat + (size_t)j * NSTATES + seg * KSEG;
        #pragma unroll
        for (int u = 0; u < 16; ++u) latr[u] = *(const float4*)(lrow + u * 4);
    }

    // thread stages its 4 polled words at padded (row tid>>4, col (tid&15)*4)
    float* dstp = &prevs[(tid >> 4) * 68 + (tid & 15) * 4];
    const float* rowp = &prevs[seg * 68];

    for (int t = 1; t < TT; ++t) {
        // E prefetch: issued before the poll; drains under the poll's wait.
        float e = E[(size_t)t * NSTATES + j];

        // ---- poll previous column: 4 relaxed agent-scope word loads/thread
        // (identical to the proven round-0 protocol), per-thread exit.
        const u32* p = (const u32*)(cols + (size_t)(t - 1) * NSTATES) + tid * 4;
        u32 w0, w1, w2, w3;
        for (;;) {
            w0 = __hip_atomic_load(p + 0, __ATOMIC_RELAXED, __HIP_MEMORY_SCOPE_AGENT);
            w1 = __hip_atomic_load(p + 1, __ATOMIC_RELAXED, __HIP_MEMORY_SCOPE_AGENT);
            w2 = __hip_atomic_load(p + 2, __ATOMIC_RELAXED, __HIP_MEMORY_SCOPE_AGENT);
            w3 = __hip_atomic_load(p + 3, __ATOMIC_RELAXED, __HIP_MEMORY_SCOPE_AGENT);
            if (w0 != SENT && w1 != SENT && w2 != SENT && w3 != SENT) break;
            __builtin_amdgcn_s_sleep(1);
        }
        {
            float4 v;
            v.x = __uint_as_float(w0);
            v.y = __uint_as_float(w1);
            v.z = __uint_as_float(w2);
            v.w = __uint_as_float(w3);
            *(float4*)dstp = v;                 // padded b128 store, conflict-free
        }
        __syncthreads();                        // barrier 1: staging visible to all

        // ---- scan this thread's 64 k's for its j: first-max (strict >, asc k)
        float best = -__builtin_inff();
        int bidx = seg * KSEG;
        #pragma unroll
        for (int u = 0; u < 16; ++u) {
            float4 q  = *(const float4*)(rowp + u * 4);   // 16-lane broadcast
            float4 wv = latr[u];
            int k0 = seg * KSEG + u * 4;
            float v0 = q.x + wv.x;
            float v1 = q.y + wv.y;
            float v2 = q.z + wv.z;
            float v3 = q.w + wv.w;
            if (v0 > best) { best = v0; bidx = k0;     }
            if (v1 > best) { best = v1; bidx = k0 + 1; }
            if (v2 > best) { best = v2; bidx = k0 + 2; }
            if (v3 > best) { best = v3; bidx = k0 + 3; }
        }

        // ---- combine the wave's 4 segs per j via shfl (disjoint ascending k
        // ranges: tie -> smaller bidx == sequential first-max). No sync.
        {
            float ov = __shfl_xor(best, 16);
            int   oi = __shfl_xor(bidx, 16);
            if (ov > best || (ov == best && oi < bidx)) { best = ov; bidx = oi; }
            ov = __shfl_xor(best, 32);
            oi = __shfl_xor(bidx, 32);
            if (ov > best || (ov == best && oi < bidx)) { best = ov; bidx = oi; }
        }
        if ((tid & 63) < JPB) {                 // one lane per (wave, jj)
            smaxw[wav][jj] = best;
            sidxw[wav][jj] = (unsigned short)bidx;
        }
        __syncthreads();                        // barrier 2: partials visible

        // ---- final 4-deep combine (ascending wave == ascending seg) + publish
        if (tid < JPB) {
            float m = smaxw[0][tid];
            int  mi = sidxw[0][tid];
            #pragma unroll
            for (int ww = 1; ww < 4; ++ww) {
                float v = smaxw[ww][tid];
                if (v > m) { m = v; mi = sidxw[ww][tid]; }
            }
            int jw = j0 + tid;
            // reference quirk: j==0 forced from state 0; prevs[0] (staged by
            // tid 0, wave 0 -- not yet overwritten) is cols[t-1][0].
            float val = (jw == 0) ? (prevs[0] + lat00) : m;
            float out = val + e;                // e: jj == tid for tid < 16
            __hip_atomic_store((u32*)(cols + (size_t)t * NSTATES) + jw,
                               __float_as_uint(out), __ATOMIC_RELAXED,
                               __HIP_MEMORY_SCOPE_AGENT);
            bptr[(size_t)t * NSTATES + jw] = (unsigned short)mi;
        }
        // no third barrier: next iteration's staging only overwrites prevs rows
        // whose readers (scans) completed before barrier 2; smaxw reuse is
        // ordered by the next iteration's barrier 1.
    }
}

#define BTC 24  // ptr rows per LDS chunk (48 KB)
__global__ void k_backtrace(const float* __restrict__ lastcol,
                            const unsigned short* __restrict__ bptr,
                            int* __restrict__ seq)
{
    __shared__ unsigned short ring[BTC][NSTATES];
    __shared__ int s_front;
    const int lane = threadIdx.x;   // 64 threads = 1 wave

    // last = first-max argmax over final column
    float best = -__builtin_inff();
    int bi = 0;
    for (int n2 = lane; n2 < NSTATES; n2 += 64) {
        float v = lastcol[n2];
        if (v > best) { best = v; bi = n2; }
    }
    #pragma unroll
    for (int off = 32; off > 0; off >>= 1) {
        float ov = __shfl_xor(best, off);
        int   oi = __shfl_xor(bi, off);
        if (ov > best || (ov == best && oi < bi)) { best = ov; bi = oi; }
    }
    if (lane == 0) { seq[TT] = bi; seq[TT - 1] = bi; s_front = bi; }
    __syncthreads();

    // chase rows r = T-1 .. 1 (seq[r-1] = ptr[r][front]) in descending LDS chunks
    for (int rhi = TT - 1; rhi >= 1; rhi -= BTC) {
        int rlo = rhi - (BTC - 1);
        if (rlo < 1) rlo = 1;
        for (int rr = rlo; rr <= rhi; ++rr) {
            const uint4* src = (const uint4*)(bptr + (size_t)rr * NSTATES);
            uint4* dst = (uint4*)(&ring[rr - rlo][0]);
            dst[lane]      = src[lane];
            dst[lane + 64] = src[lane + 64];
        }
        __syncthreads();
        if (lane == 0) {
            int front = s_front;
            for (int r = rhi; r >= rlo; --r) {
                front = (int)ring[r - rlo][front];
                seq[r - 1] = front;
            }
            s_front = front;
        }
        __syncthreads();
    }
}

extern "C" void kernel_launch(void* const* d_in, const int* in_sizes, int n_in,
                              void* d_out, int out_size, void* d_ws, size_t ws_size,
                              hipStream_t stream) {
    const float* ev    = (const float*)d_in[0];   // [T, D]
    const float* prior = (const float*)d_in[1];   // [N]
    const float* tr    = (const float*)d_in[2];   // [N, N]
    const float* epar  = (const float*)d_in[3];   // [N, D, 2]
    int* seq = (int*)d_out;                       // [T+1]
    char* ws = (char*)d_ws;
    float* lat  = (float*)(ws + OFF_LAT);
    float* E    = (float*)(ws + OFF_E);
    float* cols = (float*)(ws + OFF_COLS);
    unsigned short* bptr = (unsigned short*)(ws + OFF_PTR);

    k_init<<<4096, 256, 0, stream>>>((uint4*)cols);              // sentinel-fill 16 MB
    k_logtrans<<<4096, 256, 0, stream>>>(tr, lat);
    k_emis<<<dim3(4, TT), 256, 0, stream>>>(ev, epar, prior, E, cols);
    k_forward<<<FW_BLOCKS, FW_THREADS, 0, stream>>>(lat, E, cols, bptr);
    k_backtrace<<<1, 64, 0, stream>>>(cols + (size_t)(TT - 1) * NSTATES, bptr, seq);
}